// Round 1
// baseline (137.035 us; speedup 1.0000x reference)
//
#include <hip/hip_runtime.h>
#include <hip/hip_bf16.h>

// B=F=384, H=64, N=F*H=24576, TAU=1, EPS=1e-12
// out[b,f,g] = x[f,g] * softmax_g( qhat[b,f,:] . khat[b,g,:] )

typedef __attribute__((ext_vector_type(8))) short bf16x8;
typedef __attribute__((ext_vector_type(4))) float f32x4;

__device__ __forceinline__ ushort f2bf(float f) {
  union { __hip_bfloat16 h; ushort u; } c;
  c.h = __float2bfloat16(f);
  return c.u;
}

// ---------------- Kernel 1: q/k GEMM + L2-normalize -> bf16 in ws ----------
// grid (384, 2): x = 64-col tile (exactly one head), y = 0:Q 1:K. 256 thr.
// BM=384 (all of M, W read once), BN=64, BK=32. Wave w owns rows [96w,96w+96).
__global__ __launch_bounds__(256) void qk_gemm(
    const float* __restrict__ xin,
    const float* __restrict__ Wq, const float* __restrict__ bq,
    const float* __restrict__ Wk, const float* __restrict__ bk,
    ushort* __restrict__ qhat, ushort* __restrict__ khat)
{
  const int n0 = blockIdx.x * 64;
  const float* W    = blockIdx.y ? Wk : Wq;
  const float* bias = blockIdx.y ? bk : bq;
  ushort* outp      = blockIdx.y ? khat : qhat;

  // row stride 40 bf16 = 80 B (odd multiple of 16B -> frag reads only 2-way)
  __shared__ __align__(16) ushort Alds[384 * 40];
  __shared__ __align__(16) ushort Blds[64 * 40];

  const int tid  = threadIdx.x;
  const int wave = tid >> 6;
  const int lane = tid & 63;
  const int l15  = lane & 15;
  const int lhi  = lane >> 4;

  f32x4 acc[6][4];
  #pragma unroll
  for (int m = 0; m < 6; ++m)
    #pragma unroll
    for (int n = 0; n < 4; ++n) acc[m][n] = (f32x4)(0.f);

  for (int k0 = 0; k0 < 384; k0 += 32) {
    // stage A = x[0:384, k0:k0+32] -> bf16 LDS (3072 float4 / 256 thr)
    #pragma unroll
    for (int i = 0; i < 12; ++i) {
      int idx = tid + 256 * i;
      int row = idx >> 3, c4 = idx & 7;
      float4 v = *reinterpret_cast<const float4*>(xin + row * 384 + k0 + c4 * 4);
      ushort4 u = make_ushort4(f2bf(v.x), f2bf(v.y), f2bf(v.z), f2bf(v.w));
      *reinterpret_cast<ushort4*>(&Alds[row * 40 + c4 * 4]) = u;
    }
    // stage B = W[n0:n0+64, k0:k0+32] (row-major N x K: "B^T input" pattern)
    #pragma unroll
    for (int i = 0; i < 2; ++i) {
      int idx = tid + 256 * i;
      int row = idx >> 3, c4 = idx & 7;
      float4 v = *reinterpret_cast<const float4*>(W + (size_t)(n0 + row) * 384 + k0 + c4 * 4);
      ushort4 u = make_ushort4(f2bf(v.x), f2bf(v.y), f2bf(v.z), f2bf(v.w));
      *reinterpret_cast<ushort4*>(&Blds[row * 40 + c4 * 4]) = u;
    }
    __syncthreads();

    bf16x8 bfr[4];
    #pragma unroll
    for (int nf = 0; nf < 4; ++nf)
      bfr[nf] = *reinterpret_cast<const bf16x8*>(&Blds[(nf * 16 + l15) * 40 + lhi * 8]);
    #pragma unroll
    for (int mf = 0; mf < 6; ++mf) {
      bf16x8 afr = *reinterpret_cast<const bf16x8*>(
          &Alds[(wave * 96 + mf * 16 + l15) * 40 + lhi * 8]);
      #pragma unroll
      for (int nf = 0; nf < 4; ++nf)
        acc[mf][nf] = __builtin_amdgcn_mfma_f32_16x16x32_bf16(afr, bfr[nf], acc[mf][nf], 0, 0, 0);
    }
    __syncthreads();
  }

  // epilogue: +bias, L2-normalize over the 64 cols (= one head), write bf16.
  // C/D layout: col = lane&15, row = (lane>>4)*4 + reg  [m89]
  float bv[4];
  #pragma unroll
  for (int nf = 0; nf < 4; ++nf) bv[nf] = bias[n0 + nf * 16 + l15];

  #pragma unroll
  for (int mf = 0; mf < 6; ++mf) {
    float ss[4];
    #pragma unroll
    for (int j = 0; j < 4; ++j) {
      float s = 0.f;
      #pragma unroll
      for (int nf = 0; nf < 4; ++nf) {
        float v = acc[mf][nf][j] + bv[nf];
        acc[mf][nf][j] = v;
        s += v * v;
      }
      ss[j] = s;
    }
    #pragma unroll
    for (int m = 1; m < 16; m <<= 1) {
      #pragma unroll
      for (int j = 0; j < 4; ++j) ss[j] += __shfl_xor(ss[j], m, 64);
    }
    #pragma unroll
    for (int j = 0; j < 4; ++j) {
      float scale = 1.f / fmaxf(sqrtf(ss[j]), 1e-12f);
      int row = wave * 96 + mf * 16 + lhi * 4 + j;
      #pragma unroll
      for (int nf = 0; nf < 4; ++nf)
        outp[(size_t)row * 24576 + n0 + nf * 16 + l15] = f2bf(acc[mf][nf][j] * scale);
    }
  }
}

// ---------------- Kernel 2: scores + softmax + x*P ------------------------
// grid (12, 384): x = f-tile (32 rows), y = batch b. 256 thr (4 waves).
// Wave w owns score cols [96w, 96w+96).
__global__ __launch_bounds__(256) void attn_out(
    const float* __restrict__ xin,
    const ushort* __restrict__ qhat,
    const ushort* __restrict__ khat,
    float* __restrict__ out)
{
  const int f0 = blockIdx.x * 32;
  const int b  = blockIdx.y;

  // K tile bf16 [384][72] (55296 B); after scores, overlaid by P f32 [32][392]
  __shared__ __align__(16) char smem[384 * 72 * 2];
  ushort* Klds = reinterpret_cast<ushort*>(smem);
  float*  Slds = reinterpret_cast<float*>(smem);
  __shared__ __align__(16) ushort Qlds[32 * 72];
  __shared__ float redmax[128], redsum[128], mfin[32], invs[32];

  const int tid  = threadIdx.x;
  const int wave = tid >> 6;
  const int lane = tid & 63;
  const int l15  = lane & 15;
  const int lhi  = lane >> 4;

  // stage khat[b] (384x64 bf16) and qhat[b, f0:f0+32, :]
  #pragma unroll
  for (int i = 0; i < 12; ++i) {
    int idx = tid + 256 * i;
    int row = idx >> 3, c8 = idx & 7;
    uint4 v = *reinterpret_cast<const uint4*>(khat + (size_t)b * 24576 + row * 64 + c8 * 8);
    *reinterpret_cast<uint4*>(&Klds[row * 72 + c8 * 8]) = v;
  }
  {
    int row = tid >> 3, c8 = tid & 7;
    uint4 v = *reinterpret_cast<const uint4*>(qhat + (size_t)b * 24576 + (f0 + row) * 64 + c8 * 8);
    *reinterpret_cast<uint4*>(&Qlds[row * 72 + c8 * 8]) = v;
  }
  __syncthreads();

  // S[f, g] = sum_h qhat[f,h] khat[g,h];  A = qhat (M=32), B = khat^T
  f32x4 acc[2][6];
  #pragma unroll
  for (int m = 0; m < 2; ++m)
    #pragma unroll
    for (int n = 0; n < 6; ++n) acc[m][n] = (f32x4)(0.f);

  #pragma unroll
  for (int ks = 0; ks < 2; ++ks) {
    bf16x8 aq[2];
    #pragma unroll
    for (int mf = 0; mf < 2; ++mf)
      aq[mf] = *reinterpret_cast<const bf16x8*>(&Qlds[(mf * 16 + l15) * 72 + ks * 32 + lhi * 8]);
    #pragma unroll
    for (int nf = 0; nf < 6; ++nf) {
      bf16x8 bk8 = *reinterpret_cast<const bf16x8*>(
          &Klds[(wave * 96 + nf * 16 + l15) * 72 + ks * 32 + lhi * 8]);
      #pragma unroll
      for (int mf = 0; mf < 2; ++mf)
        acc[mf][nf] = __builtin_amdgcn_mfma_f32_16x16x32_bf16(aq[mf], bk8, acc[mf][nf], 0, 0, 0);
    }
  }

  // per-row max: in-reg over 6 n-frags, butterfly over lane&15, then x-wave LDS
  #pragma unroll
  for (int mf = 0; mf < 2; ++mf) {
    #pragma unroll
    for (int j = 0; j < 4; ++j) {
      float m = acc[mf][0][j];
      #pragma unroll
      for (int nf = 1; nf < 6; ++nf) m = fmaxf(m, acc[mf][nf][j]);
      #pragma unroll
      for (int s = 1; s < 16; s <<= 1) m = fmaxf(m, __shfl_xor(m, s, 64));
      if (l15 == 0) redmax[wave * 32 + mf * 16 + lhi * 4 + j] = m;
    }
  }
  __syncthreads();   // also fences all Klds reads before the P overlay below
  if (tid < 32)
    mfin[tid] = fmaxf(fmaxf(redmax[tid], redmax[32 + tid]),
                      fmaxf(redmax[64 + tid], redmax[96 + tid]));
  __syncthreads();

  // exp (TAU=1 so no scale), stage P into Slds, reduce row sums
  #pragma unroll
  for (int mf = 0; mf < 2; ++mf) {
    #pragma unroll
    for (int j = 0; j < 4; ++j) {
      int r = mf * 16 + lhi * 4 + j;
      float m = mfin[r];
      float s = 0.f;
      #pragma unroll
      for (int nf = 0; nf < 6; ++nf) {
        float p = __expf(acc[mf][nf][j] - m);
        Slds[r * 392 + wave * 96 + nf * 16 + l15] = p;
        s += p;
      }
      #pragma unroll
      for (int sh = 1; sh < 16; sh <<= 1) s += __shfl_xor(s, sh, 64);
      if (l15 == 0) redsum[wave * 32 + r] = s;
    }
  }
  __syncthreads();
  if (tid < 32)
    invs[tid] = 1.f / (redsum[tid] + redsum[32 + tid] + redsum[64 + tid] + redsum[96 + tid]);
  __syncthreads();

  // coalesced output: out[b, f0+r, g] = x[f0+r, g] * P[r][g] * invs[r]
  #pragma unroll
  for (int i = 0; i < 12; ++i) {
    int idx = tid + 256 * i;            // 0..3071 ; 96 float4 per row
    int row = idx / 96, c = idx - row * 96;
    float iv = invs[row];
    float4 p4 = *reinterpret_cast<const float4*>(&Slds[row * 392 + c * 4]);
    float4 x4 = *reinterpret_cast<const float4*>(xin + (size_t)(f0 + row) * 384 + c * 4);
    float4 o;
    o.x = x4.x * p4.x * iv;  o.y = x4.y * p4.y * iv;
    o.z = x4.z * p4.z * iv;  o.w = x4.w * p4.w * iv;
    *reinterpret_cast<float4*>(out + (size_t)b * 147456 + (size_t)(f0 + row) * 384 + c * 4) = o;
  }
}

extern "C" void kernel_launch(void* const* d_in, const int* in_sizes, int n_in,
                              void* d_out, int out_size, void* d_ws, size_t ws_size,
                              hipStream_t stream) {
  const float* x  = (const float*)d_in[0];
  const float* Wq = (const float*)d_in[1];
  const float* bq = (const float*)d_in[2];
  const float* Wk = (const float*)d_in[3];
  const float* bk = (const float*)d_in[4];
  float* out = (float*)d_out;

  // ws: qhat [384*24576] bf16, khat [384*24576] bf16 = 37.75 MB total
  ushort* qhat = (ushort*)d_ws;
  ushort* khat = qhat + (size_t)384 * 24576;

  dim3 g1(384, 2), b1(256);
  qk_gemm<<<g1, b1, 0, stream>>>(x, Wq, bq, Wk, bk, qhat, khat);

  dim3 g2(12, 384), b2(256);
  attn_out<<<g2, b2, 0, stream>>>(x, qhat, khat, out);
}

// Round 2
// 126.484 us; speedup vs baseline: 1.0834x; 1.0834x over previous
//
#include <hip/hip_runtime.h>
#include <hip/hip_bf16.h>

// B=F=384, H=64, N=F*H=24576, TAU=1, EPS=1e-12
// out[b,f,g] = x[f,g] * softmax_g( qhat[b,f,:] . khat[b,g,:] )

typedef __attribute__((ext_vector_type(8))) short bf16x8;
typedef __attribute__((ext_vector_type(4))) float f32x4;

__device__ __forceinline__ ushort f2bf(float f) {
  union { __hip_bfloat16 h; ushort u; } c;
  c.h = __float2bfloat16(f);
  return c.u;
}

__device__ __forceinline__ void load_lds16(const void* g, void* l) {
  __builtin_amdgcn_global_load_lds(
      (const __attribute__((address_space(1))) void*)g,
      (__attribute__((address_space(3))) void*)l, 16, 0, 0);
}

// ---------------- Kernel 0: x -> bf16, pre-swizzled for global_load_lds ----
// Layout: tile kt (K-chunk of 32), row m, slot s' (4 x 8 bf16):
//   xbf[kt*12288 + m*32 + s'*8 + w] = x[m][kt*32 + (s'^((m>>1)&3))*8 + w]
// so a LINEAR gload_lds of the tile lands swizzled in LDS; frag reads XOR back.
__global__ __launch_bounds__(256) void xconv(const float* __restrict__ xin,
                                             ushort* __restrict__ xbf) {
  int t = blockIdx.x * 256 + threadIdx.x;   // 18432 threads, 8 bf16 each
  int o = t * 8;
  int kt = o / 12288;
  int rem = o - kt * 12288;
  int m = rem >> 5;
  int sp = (rem >> 3) & 3;
  int slot = sp ^ ((m >> 1) & 3);
  const float* src = xin + m * 384 + kt * 32 + slot * 8;
  float4 a = *reinterpret_cast<const float4*>(src);
  float4 b = *reinterpret_cast<const float4*>(src + 4);
  ushort4 u0 = make_ushort4(f2bf(a.x), f2bf(a.y), f2bf(a.z), f2bf(a.w));
  ushort4 u1 = make_ushort4(f2bf(b.x), f2bf(b.y), f2bf(b.z), f2bf(b.w));
  *reinterpret_cast<ushort4*>(xbf + o)     = u0;
  *reinterpret_cast<ushort4*>(xbf + o + 4) = u1;
}

// ---------------- Kernel 1: q/k GEMM + L2-normalize -> swizzled bf16 -------
// grid (384, 2): x = head (64 cols of N), y = 0:Q 1:K. 256 thr, 4 waves.
// BM=384 (W read once), BN=64, BK=32. Wave w owns M-rows [96w, 96w+96).
// A staged via global_load_lds from pre-swizzled xbf (linear LDS, no VALU).
__global__ __launch_bounds__(256) void qk_gemm(
    const ushort* __restrict__ xbf,
    const float* __restrict__ Wq, const float* __restrict__ bq,
    const float* __restrict__ Wk, const float* __restrict__ bk,
    ushort* __restrict__ qhat, ushort* __restrict__ khat)
{
  const int bx = blockIdx.x;
  const int n0 = bx * 64;
  const float* W    = blockIdx.y ? Wk : Wq;
  const float* bias = blockIdx.y ? bk : bq;
  ushort* outp      = blockIdx.y ? khat : qhat;

  __shared__ __align__(16) ushort Alds[384 * 32];  // 24 KB, swizzled-linear
  __shared__ __align__(16) ushort Blds[64 * 40];   // 5 KB, +8 pad

  const int tid  = threadIdx.x;
  const int wave = tid >> 6;
  const int lane = tid & 63;
  const int l15  = lane & 15;
  const int lhi  = lane >> 4;

  f32x4 acc[6][4];
  #pragma unroll
  for (int m = 0; m < 6; ++m)
    #pragma unroll
    for (int n = 0; n < 4; ++n) acc[m][n] = (f32x4)(0.f);

  const int aslot = lhi ^ ((l15 >> 1) & 3);   // A frag read swizzle (const/lane)

  for (int kt = 0; kt < 12; ++kt) {
    // stage A: 24 KB = 24 x 1KB wave-chunks, 6 per wave, zero VALU
    const ushort* asrc = xbf + kt * 12288 + lane * 8;
    #pragma unroll
    for (int i = 0; i < 6; ++i) {
      int chunk = wave * 6 + i;
      load_lds16(asrc + chunk * 512, (char*)Alds + chunk * 1024);
    }
    // stage B = W[n0:n0+64, k0:k0+32] with f32->bf16 convert (2 float4/thr)
    #pragma unroll
    for (int i = 0; i < 2; ++i) {
      int idx = tid + 256 * i;
      int row = idx >> 3, c4 = idx & 7;
      float4 v = *reinterpret_cast<const float4*>(
          W + (size_t)(n0 + row) * 384 + kt * 32 + c4 * 4);
      ushort4 u = make_ushort4(f2bf(v.x), f2bf(v.y), f2bf(v.z), f2bf(v.w));
      *reinterpret_cast<ushort4*>(&Blds[row * 40 + c4 * 4]) = u;
    }
    __syncthreads();

    bf16x8 bfr[4];
    #pragma unroll
    for (int nf = 0; nf < 4; ++nf)
      bfr[nf] = *reinterpret_cast<const bf16x8*>(&Blds[(nf * 16 + l15) * 40 + lhi * 8]);
    #pragma unroll
    for (int mf = 0; mf < 6; ++mf) {
      int rr = wave * 96 + mf * 16 + l15;
      bf16x8 afr = *reinterpret_cast<const bf16x8*>(&Alds[rr * 32 + aslot * 8]);
      #pragma unroll
      for (int nf = 0; nf < 4; ++nf)
        acc[mf][nf] = __builtin_amdgcn_mfma_f32_16x16x32_bf16(afr, bfr[nf], acc[mf][nf], 0, 0, 0);
    }
    __syncthreads();
  }

  // epilogue: +bias, L2-normalize over 64 cols (one head), write swizzled bf16
  // C/D layout: col = lane&15, row = (lane>>4)*4 + reg  [m89]
  float bv[4];
  int hp[4];
  const int sw = bx & 7;
  #pragma unroll
  for (int nf = 0; nf < 4; ++nf) {
    bv[nf] = bias[n0 + nf * 16 + l15];
    hp[nf] = (((nf * 2 + (l15 >> 3)) ^ sw) << 3) + (l15 & 7);  // swizzled h
  }

  #pragma unroll
  for (int mf = 0; mf < 6; ++mf) {
    float ss[4];
    #pragma unroll
    for (int j = 0; j < 4; ++j) {
      float s = 0.f;
      #pragma unroll
      for (int nf = 0; nf < 4; ++nf) {
        float v = acc[mf][nf][j] + bv[nf];
        acc[mf][nf][j] = v;
        s += v * v;
      }
      ss[j] = s;
    }
    #pragma unroll
    for (int m = 1; m < 16; m <<= 1) {
      #pragma unroll
      for (int j = 0; j < 4; ++j) ss[j] += __shfl_xor(ss[j], m, 64);
    }
    #pragma unroll
    for (int j = 0; j < 4; ++j) {
      float scale = 1.f / fmaxf(sqrtf(ss[j]), 1e-12f);
      int row = wave * 96 + mf * 16 + lhi * 4 + j;   // = b index
      #pragma unroll
      for (int nf = 0; nf < 4; ++nf)
        outp[(size_t)row * 24576 + n0 + hp[nf]] = f2bf(acc[mf][nf][j] * scale);
    }
  }
}

// ---------------- Kernel 2: scores + softmax + x*P ------------------------
// grid (12, 384): x = f-tile (32 rows), y = batch b. 256 thr (4 waves).
// Wave w owns score cols [96w, 96w+96). K staged via gload_lds (swizzled ws),
// Q frags straight from global into VGPRs. LDS ~51 KB -> 3 blocks/CU.
#define PSTR 396
__global__ __launch_bounds__(256) void attn_out(
    const float* __restrict__ xin,
    const ushort* __restrict__ qhat,
    const ushort* __restrict__ khat,
    float* __restrict__ out)
{
  const int f0 = blockIdx.x * 32;
  const int b  = blockIdx.y;

  // union: K bf16 [384][64] swizzled (48 KB)  |  P f32 [32][PSTR] (49.5 KB)
  __shared__ __align__(16) char smem[32 * PSTR * 4];
  ushort* Klds = reinterpret_cast<ushort*>(smem);
  float*  Slds = reinterpret_cast<float*>(smem);
  __shared__ float redmax[128], redsum[128], mfin[32], invs[32];

  const int tid  = threadIdx.x;
  const int wave = tid >> 6;
  const int lane = tid & 63;
  const int l15  = lane & 15;
  const int lhi  = lane >> 4;

  // stage khat[b] (48 KB = 48 x 1KB chunks, 12 per wave)
  const ushort* ksrc = khat + (size_t)b * 24576 + lane * 8;
  #pragma unroll
  for (int i = 0; i < 12; ++i) {
    int chunk = wave * 12 + i;
    load_lds16(ksrc + chunk * 512, smem + chunk * 1024);
  }

  // Q frags direct from global (L2-hot; 12 blocks share b)
  bf16x8 aq[2][2];
  #pragma unroll
  for (int mf = 0; mf < 2; ++mf)
    #pragma unroll
    for (int ks = 0; ks < 2; ++ks)
      aq[mf][ks] = *reinterpret_cast<const bf16x8*>(
          qhat + (size_t)b * 24576 + (f0 + mf * 16 + l15) * 64 +
          (((ks * 4 + lhi) ^ (l15 & 7)) << 3));
  __syncthreads();

  // S = qhat . khat^T : acc[mf][nf], wave covers g in [96w, 96w+96)
  f32x4 acc[2][6];
  #pragma unroll
  for (int m = 0; m < 2; ++m)
    #pragma unroll
    for (int n = 0; n < 6; ++n) acc[m][n] = (f32x4)(0.f);

  #pragma unroll
  for (int ks = 0; ks < 2; ++ks) {
    #pragma unroll
    for (int nf = 0; nf < 6; ++nf) {
      int rr = wave * 96 + nf * 16 + l15;
      bf16x8 bk8 = *reinterpret_cast<const bf16x8*>(
          &Klds[rr * 64 + (((ks * 4 + lhi) ^ (l15 & 7)) << 3)]);
      #pragma unroll
      for (int mf = 0; mf < 2; ++mf)
        acc[mf][nf] = __builtin_amdgcn_mfma_f32_16x16x32_bf16(aq[mf][ks], bk8, acc[mf][nf], 0, 0, 0);
    }
  }

  // per-row max: in-reg over 6 n-frags, butterfly over 16, then cross-wave
  #pragma unroll
  for (int mf = 0; mf < 2; ++mf) {
    #pragma unroll
    for (int j = 0; j < 4; ++j) {
      float m = acc[mf][0][j];
      #pragma unroll
      for (int nf = 1; nf < 6; ++nf) m = fmaxf(m, acc[mf][nf][j]);
      #pragma unroll
      for (int s = 1; s < 16; s <<= 1) m = fmaxf(m, __shfl_xor(m, s, 64));
      if (l15 == 0) redmax[wave * 32 + mf * 16 + lhi * 4 + j] = m;
    }
  }
  __syncthreads();   // all Klds reads done -> P may overlay
  if (tid < 32)
    mfin[tid] = fmaxf(fmaxf(redmax[tid], redmax[32 + tid]),
                      fmaxf(redmax[64 + tid], redmax[96 + tid]));
  __syncthreads();

  // exp (TAU=1), stage P into overlay, reduce row sums
  #pragma unroll
  for (int mf = 0; mf < 2; ++mf) {
    #pragma unroll
    for (int j = 0; j < 4; ++j) {
      int r = mf * 16 + lhi * 4 + j;
      float m = mfin[r];
      float s = 0.f;
      #pragma unroll
      for (int nf = 0; nf < 6; ++nf) {
        float p = __expf(acc[mf][nf][j] - m);
        Slds[r * PSTR + wave * 96 + nf * 16 + l15] = p;
        s += p;
      }
      #pragma unroll
      for (int sh = 1; sh < 16; sh <<= 1) s += __shfl_xor(s, sh, 64);
      if (l15 == 0) redsum[wave * 32 + r] = s;
    }
  }
  __syncthreads();
  if (tid < 32)
    invs[tid] = 1.f / (redsum[tid] + redsum[32 + tid] + redsum[64 + tid] + redsum[96 + tid]);
  __syncthreads();

  // coalesced output: out[b, f0+r, g] = x[f0+r, g] * P[r][g] * invs[r]
  #pragma unroll
  for (int i = 0; i < 12; ++i) {
    int idx = tid + 256 * i;            // 32 rows x 96 float4
    int row = idx / 96, c = idx - row * 96;
    float iv = invs[row];
    float4 p4 = *reinterpret_cast<const float4*>(&Slds[row * PSTR + c * 4]);
    float4 x4 = *reinterpret_cast<const float4*>(xin + (size_t)(f0 + row) * 384 + c * 4);
    float4 o;
    o.x = x4.x * p4.x * iv;  o.y = x4.y * p4.y * iv;
    o.z = x4.z * p4.z * iv;  o.w = x4.w * p4.w * iv;
    *reinterpret_cast<float4*>(out + (size_t)b * 147456 + (size_t)(f0 + row) * 384 + c * 4) = o;
  }
}

extern "C" void kernel_launch(void* const* d_in, const int* in_sizes, int n_in,
                              void* d_out, int out_size, void* d_ws, size_t ws_size,
                              hipStream_t stream) {
  const float* x  = (const float*)d_in[0];
  const float* Wq = (const float*)d_in[1];
  const float* bq = (const float*)d_in[2];
  const float* Wk = (const float*)d_in[3];
  const float* bk = (const float*)d_in[4];
  float* out = (float*)d_out;

  // ws: qhat + khat (2 x 18.87 MB, swizzled bf16) + xbf (288 KB, swizzled bf16)
  ushort* qhat = (ushort*)d_ws;
  ushort* khat = qhat + (size_t)384 * 24576;
  ushort* xbf  = khat + (size_t)384 * 24576;

  xconv<<<dim3(72), dim3(256), 0, stream>>>(x, xbf);

  dim3 g1(384, 2), b1(256);
  qk_gemm<<<g1, b1, 0, stream>>>(xbf, Wq, bq, Wk, bk, qhat, khat);

  dim3 g2(12, 384), b2(256);
  attn_out<<<g2, b2, 0, stream>>>(x, qhat, khat, out);
}